// Round 1
// baseline (188.525 us; speedup 1.0000x reference)
//
#include <hip/hip_runtime.h>
#include <hip/hip_bf16.h>
#include <stdint.h>

#define DIM 1024
#define NHEADS 16
#define HDIM 64
#define BB 2
#define SS 2048
#define MTOT (BB * SS)  // 4096

typedef __attribute__((ext_vector_type(4))) float f32x4;
typedef __attribute__((ext_vector_type(8))) short bf16x8;
typedef __attribute__((ext_vector_type(4))) short sh4;

__device__ inline short f2bf(float f) {
  uint32_t u = __float_as_uint(f);
  uint32_t r = (u + 0x7fffu + ((u >> 16) & 1u)) >> 16;
  return (short)(uint16_t)r;
}

// ---------------- cast x (fp32 -> bf16) ----------------
__global__ void cast_x_kernel(const float4* __restrict__ x, sh4* __restrict__ out) {
  int i = blockIdx.x * blockDim.x + threadIdx.x;
  float4 v = x[i];
  sh4 o;
  o[0] = f2bf(v.x); o[1] = f2bf(v.y); o[2] = f2bf(v.z); o[3] = f2bf(v.w);
  out[i] = o;
}

// ---------------- transpose + cast W (fp32 [k][n] -> bf16 [n][k]) ----------------
__global__ void transpose_w_kernel(const float* __restrict__ Wq, const float* __restrict__ Wk,
                                   const float* __restrict__ Wv, short* __restrict__ wt) {
  const float* W = blockIdx.z == 0 ? Wq : (blockIdx.z == 1 ? Wk : Wv);
  short* o = wt + (size_t)blockIdx.z * DIM * DIM;
  __shared__ float t[32][33];
  int n = blockIdx.x * 32 + threadIdx.x;
  int kk = blockIdx.y * 32 + threadIdx.y;
  t[threadIdx.y][threadIdx.x] = W[(size_t)kk * DIM + n];
  __syncthreads();
  int on = blockIdx.x * 32 + threadIdx.y;
  int ok = blockIdx.y * 32 + threadIdx.x;
  o[(size_t)on * DIM + ok] = f2bf(t[threadIdx.x][threadIdx.y]);
}

// ---------------- fused QKV GEMM ----------------
// C[m][n] = sum_k X[m][k] * Wt[n][k]  (+bias). z=0:Q(*0.125, [B,H,S,dh]) z=1:K([B,H,S,dh]) z=2:V^T([B,H,dh,S])
#define BKP 40  // padded LDS row stride (elements): 80B, 16B-aligned, bank-conflict-free
__global__ __launch_bounds__(256) void qkv_gemm_kernel(
    const short* __restrict__ xb, const short* __restrict__ wt,
    const float* __restrict__ bq, const float* __restrict__ bk, const float* __restrict__ bv,
    short* __restrict__ qo, short* __restrict__ ko, short* __restrict__ vto) {
  __shared__ short As[128 * BKP];
  __shared__ short Bs[128 * BKP];
  const int tid = threadIdx.x;
  const int lane = tid & 63, wave = tid >> 6;
  const int lr = lane & 15, lg = lane >> 4;
  const int m0 = blockIdx.y * 128, n0 = blockIdx.x * 128;
  const int z = blockIdx.z;
  const short* wz = wt + (size_t)z * DIM * DIM;

  f32x4 acc[4][4];
#pragma unroll
  for (int i = 0; i < 4; i++)
#pragma unroll
    for (int j = 0; j < 4; j++) acc[i][j] = (f32x4){0.f, 0.f, 0.f, 0.f};

  const int wr = (wave >> 1) * 64, wc = (wave & 1) * 64;
  const int r0 = tid >> 2, kc = tid & 3;  // staging: row, k-chunk

  for (int kt = 0; kt < DIM; kt += 32) {
    uint4 a0 = *(const uint4*)(xb + (size_t)(m0 + r0) * DIM + kt + kc * 8);
    uint4 a1 = *(const uint4*)(xb + (size_t)(m0 + r0 + 64) * DIM + kt + kc * 8);
    uint4 b0 = *(const uint4*)(wz + (size_t)(n0 + r0) * DIM + kt + kc * 8);
    uint4 b1 = *(const uint4*)(wz + (size_t)(n0 + r0 + 64) * DIM + kt + kc * 8);
    __syncthreads();
    *(uint4*)&As[r0 * BKP + kc * 8] = a0;
    *(uint4*)&As[(r0 + 64) * BKP + kc * 8] = a1;
    *(uint4*)&Bs[r0 * BKP + kc * 8] = b0;
    *(uint4*)&Bs[(r0 + 64) * BKP + kc * 8] = b1;
    __syncthreads();
    bf16x8 af[4], bf[4];
#pragma unroll
    for (int i = 0; i < 4; i++) af[i] = *(const bf16x8*)&As[(wr + i * 16 + lr) * BKP + lg * 8];
#pragma unroll
    for (int j = 0; j < 4; j++) bf[j] = *(const bf16x8*)&Bs[(wc + j * 16 + lr) * BKP + lg * 8];
#pragma unroll
    for (int i = 0; i < 4; i++)
#pragma unroll
      for (int j = 0; j < 4; j++)
        acc[i][j] = __builtin_amdgcn_mfma_f32_16x16x32_bf16(af[i], bf[j], acc[i][j], 0, 0, 0);
  }

  const float* bias = z == 0 ? bq : (z == 1 ? bk : bv);
#pragma unroll
  for (int j = 0; j < 4; j++) {
    int n = n0 + wc + j * 16 + lr;
    float bn = bias[n];
    int hh = n >> 6, dd = n & 63;
#pragma unroll
    for (int i = 0; i < 4; i++) {
      int mbase = m0 + wr + i * 16 + lg * 4;  // multiple of 4, never crosses S boundary
      int bb = mbase >> 11, s = mbase & 2047;
      if (z == 2) {
        sh4 pk;
#pragma unroll
        for (int r = 0; r < 4; r++) pk[r] = f2bf(acc[i][j][r] + bn);
        *(sh4*)(vto + ((size_t)(bb * NHEADS + hh) * HDIM + dd) * SS + s) = pk;
      } else {
        short* o = (z == 0 ? qo : ko);
        float scl = (z == 0 ? 0.125f : 1.0f);
#pragma unroll
        for (int r = 0; r < 4; r++)
          o[((size_t)(bb * NHEADS + hh) * SS + s + r) * HDIM + dd] = f2bf((acc[i][j][r] + bn) * scl);
      }
    }
  }
}

// ---------------- flash attention ----------------
#define KVP 72  // padded LDS row stride (elements): 144B, 16B-aligned
__global__ __launch_bounds__(256) void attn_kernel(const short* __restrict__ q, const short* __restrict__ k,
                                                   const short* __restrict__ vt, float* __restrict__ out) {
  __shared__ short Ks[64 * KVP];
  __shared__ short Vs[64 * KVP];
  __shared__ short Ps[4][16 * KVP];
  const int tid = threadIdx.x, lane = tid & 63, wave = tid >> 6;
  const int lr = lane & 15, lg = lane >> 4;
  const int qt = blockIdx.x, h = blockIdx.y, b = blockIdx.z;
  const int bh = b * NHEADS + h;
  const short* qp = q + (size_t)bh * SS * HDIM;
  const short* kp = k + (size_t)bh * SS * HDIM;
  const short* vp = vt + (size_t)bh * HDIM * SS;
  const int q0 = qt * 64 + wave * 16;

  bf16x8 aq[2];
#pragma unroll
  for (int ks = 0; ks < 2; ks++)
    aq[ks] = *(const bf16x8*)(qp + (size_t)(q0 + lr) * HDIM + ks * 32 + lg * 8);

  f32x4 accO[4];
#pragma unroll
  for (int dj = 0; dj < 4; dj++) accO[dj] = (f32x4){0.f, 0.f, 0.f, 0.f};
  float mrow[4], lrow[4];
#pragma unroll
  for (int r = 0; r < 4; r++) { mrow[r] = -1e30f; lrow[r] = 0.f; }

  const int c0 = tid, c1 = tid + 256;
  for (int kt = 0; kt < SS; kt += 64) {
    __syncthreads();
    *(uint4*)&Ks[(c0 >> 3) * KVP + (c0 & 7) * 8] = *(const uint4*)(kp + (size_t)(kt + (c0 >> 3)) * HDIM + (c0 & 7) * 8);
    *(uint4*)&Ks[(c1 >> 3) * KVP + (c1 & 7) * 8] = *(const uint4*)(kp + (size_t)(kt + (c1 >> 3)) * HDIM + (c1 & 7) * 8);
    *(uint4*)&Vs[(c0 >> 3) * KVP + (c0 & 7) * 8] = *(const uint4*)(vp + (size_t)(c0 >> 3) * SS + kt + (c0 & 7) * 8);
    *(uint4*)&Vs[(c1 >> 3) * KVP + (c1 & 7) * 8] = *(const uint4*)(vp + (size_t)(c1 >> 3) * SS + kt + (c1 & 7) * 8);
    __syncthreads();

    // scores: S = Q @ K^T (Q pre-scaled by 1/8)
    f32x4 sc[4];
#pragma unroll
    for (int j = 0; j < 4; j++) {
      bf16x8 kb0 = *(const bf16x8*)&Ks[(j * 16 + lr) * KVP + lg * 8];
      bf16x8 kb1 = *(const bf16x8*)&Ks[(j * 16 + lr) * KVP + 32 + lg * 8];
      f32x4 z4 = (f32x4){0.f, 0.f, 0.f, 0.f};
      sc[j] = __builtin_amdgcn_mfma_f32_16x16x32_bf16(aq[0], kb0, z4, 0, 0, 0);
      sc[j] = __builtin_amdgcn_mfma_f32_16x16x32_bf16(aq[1], kb1, sc[j], 0, 0, 0);
    }

    // online softmax (per q-row; 16 lanes of a quarter hold 16 keys of the same row)
#pragma unroll
    for (int r = 0; r < 4; r++) {
      float mx = fmaxf(fmaxf(sc[0][r], sc[1][r]), fmaxf(sc[2][r], sc[3][r]));
#pragma unroll
      for (int msk = 1; msk < 16; msk <<= 1) mx = fmaxf(mx, __shfl_xor(mx, msk, 64));
      float mnew = fmaxf(mrow[r], mx);
      float scal = __expf(mrow[r] - mnew);
      float s0 = 0.f;
#pragma unroll
      for (int j = 0; j < 4; j++) {
        float p = __expf(sc[j][r] - mnew);
        sc[j][r] = p;
        s0 += p;
      }
#pragma unroll
      for (int msk = 1; msk < 16; msk <<= 1) s0 += __shfl_xor(s0, msk, 64);
      lrow[r] = lrow[r] * scal + s0;
      mrow[r] = mnew;
#pragma unroll
      for (int dj = 0; dj < 4; dj++) accO[dj][r] *= scal;
    }

    // P -> LDS (per-wave region; same-wave RAW through LDS is in-order)
    short* pw = &Ps[wave][0];
#pragma unroll
    for (int r = 0; r < 4; r++)
#pragma unroll
      for (int j = 0; j < 4; j++)
        pw[(lg * 4 + r) * KVP + j * 16 + lr] = f2bf(sc[j][r]);

    // PV: O += P @ V
    bf16x8 pa0 = *(const bf16x8*)&pw[lr * KVP + lg * 8];
    bf16x8 pa1 = *(const bf16x8*)&pw[lr * KVP + 32 + lg * 8];
#pragma unroll
    for (int dj = 0; dj < 4; dj++) {
      bf16x8 v0 = *(const bf16x8*)&Vs[(dj * 16 + lr) * KVP + lg * 8];
      bf16x8 v1 = *(const bf16x8*)&Vs[(dj * 16 + lr) * KVP + 32 + lg * 8];
      accO[dj] = __builtin_amdgcn_mfma_f32_16x16x32_bf16(pa0, v0, accO[dj], 0, 0, 0);
      accO[dj] = __builtin_amdgcn_mfma_f32_16x16x32_bf16(pa1, v1, accO[dj], 0, 0, 0);
    }
  }

  // epilogue: out[b][s][h*64+d] = O / l
#pragma unroll
  for (int dj = 0; dj < 4; dj++) {
    int d = h * HDIM + dj * 16 + lr;
#pragma unroll
    for (int r = 0; r < 4; r++) {
      int s = q0 + lg * 4 + r;
      out[((size_t)b * SS + s) * DIM + d] = accO[dj][r] / lrow[r];
    }
  }
}

extern "C" void kernel_launch(void* const* d_in, const int* in_sizes, int n_in,
                              void* d_out, int out_size, void* d_ws, size_t ws_size,
                              hipStream_t stream) {
  const float* x  = (const float*)d_in[0];
  const float* Wq = (const float*)d_in[1];
  const float* bq = (const float*)d_in[2];
  const float* Wk = (const float*)d_in[3];
  const float* bk = (const float*)d_in[4];
  const float* Wv = (const float*)d_in[5];
  const float* bv = (const float*)d_in[6];
  float* out = (float*)d_out;

  char* ws = (char*)d_ws;
  short* xb  = (short*)ws;                    // 8 MB: x bf16 [4096][1024]
  short* wt  = (short*)(ws + (8u << 20));     // 6 MB: W^T bf16 [3][1024][1024]
  short* qb  = (short*)(ws + (14u << 20));    // 8 MB: Q bf16 [B,H,S,dh] (pre-scaled)
  short* kb  = (short*)(ws + (22u << 20));    // 8 MB: K bf16 [B,H,S,dh]
  short* vtb = (short*)(ws + (30u << 20));    // 8 MB: V^T bf16 [B,H,dh,S]

  cast_x_kernel<<<dim3(MTOT * DIM / 4 / 256), 256, 0, stream>>>((const float4*)x, (sh4*)xb);
  transpose_w_kernel<<<dim3(32, 32, 3), dim3(32, 32), 0, stream>>>(Wq, Wk, Wv, wt);
  qkv_gemm_kernel<<<dim3(8, 32, 3), 256, 0, stream>>>(xb, wt, bq, bk, bv, qb, kb, vtb);
  attn_kernel<<<dim3(SS / 64, NHEADS, BB), 256, 0, stream>>>(qb, kb, vtb, out);
}